// Round 3
// baseline (116.694 us; speedup 1.0000x reference)
//
#include <hip/hip_runtime.h>
#include <math.h>

#define GEO_N 256

__device__ __forceinline__ float wredf(float v) {
#pragma unroll
  for (int off = 32; off; off >>= 1) v += __shfl_xor(v, off, 64);
  return v;
}

// One Jacobi rotation on symmetric G (both sides) + accumulate into V.
template <int P, int Q>
__device__ __forceinline__ void jrot(float G[3][3], float V[3][3]) {
  float apq = G[P][Q];
  if (fabsf(apq) < 1e-22f) return;
  float tau = (G[Q][Q] - G[P][P]) / (2.0f * apq);
  float tt = sqrtf(1.0f + tau * tau);
  float t = (tau >= 0.0f) ? (1.0f / (tau + tt)) : (1.0f / (tau - tt));
  float c = 1.0f / sqrtf(1.0f + t * t);
  float s = t * c;
#pragma unroll
  for (int k = 0; k < 3; ++k) {
    float gkp = G[k][P], gkq = G[k][Q];
    G[k][P] = c * gkp - s * gkq;
    G[k][Q] = s * gkp + c * gkq;
  }
#pragma unroll
  for (int k = 0; k < 3; ++k) {
    float gpk = G[P][k], gqk = G[Q][k];
    G[P][k] = c * gpk - s * gqk;
    G[Q][k] = s * gpk + c * gqk;
  }
#pragma unroll
  for (int k = 0; k < 3; ++k) {
    float vkp = V[k][P], vkq = V[k][Q];
    V[k][P] = c * vkp - s * vkq;
    V[k][Q] = s * vkp + c * vkq;
  }
}

// From 16 raw moment sums -> R(9), scale, T(3) packed into bc[0..12].
// s0: Ssrc(3) Sdst(3) M_ij=sum dst_i*src_j (9, row-major i) q=sum|src|^2 (1)
// All indices compile-time -> registers, no scratch.
__device__ __forceinline__ void solve_rst(const float s0[16], float bc[13]) {
  const float invN = 1.0f / (float)GEO_N;
  const float smx = s0[0] * invN, smy = s0[1] * invN, smz = s0[2] * invN;
  const float dmx = s0[3] * invN, dmy = s0[4] * invN, dmz = s0[5] * invN;
  float A[3][3];
  A[0][0] = s0[6] * invN - dmx * smx;  A[0][1] = s0[7] * invN - dmx * smy;  A[0][2] = s0[8] * invN - dmx * smz;
  A[1][0] = s0[9] * invN - dmy * smx;  A[1][1] = s0[10] * invN - dmy * smy; A[1][2] = s0[11] * invN - dmy * smz;
  A[2][0] = s0[12] * invN - dmz * smx; A[2][1] = s0[13] * invN - dmz * smy; A[2][2] = s0[14] * invN - dmz * smz;
  const float var_sum = s0[15] * invN - (smx * smx + smy * smy + smz * smz);

  // G = A^T A (symmetric PSD), Jacobi eigensolve -> V, lambda
  float G[3][3];
#pragma unroll
  for (int i = 0; i < 3; ++i)
#pragma unroll
    for (int j = 0; j < 3; ++j)
      G[i][j] = A[0][i] * A[0][j] + A[1][i] * A[1][j] + A[2][i] * A[2][j];
  float V[3][3] = {{1, 0, 0}, {0, 1, 0}, {0, 0, 1}};
#pragma unroll 1
  for (int sweep = 0; sweep < 8; ++sweep) {
    float off = G[0][1] * G[0][1] + G[0][2] * G[0][2] + G[1][2] * G[1][2];
    float dia = G[0][0] * G[0][0] + G[1][1] * G[1][1] + G[2][2] * G[2][2];
    if (off <= 1e-13f * dia + 1e-30f) break;
    jrot<0, 1>(G, V);
    jrot<0, 2>(G, V);
    jrot<1, 2>(G, V);
  }
  float l0 = G[0][0], l1 = G[1][1], l2 = G[2][2];
  if (l0 < l1) { float tl = l0; l0 = l1; l1 = tl;
#pragma unroll
    for (int k = 0; k < 3; ++k) { float tv = V[k][0]; V[k][0] = V[k][1]; V[k][1] = tv; } }
  if (l0 < l2) { float tl = l0; l0 = l2; l2 = tl;
#pragma unroll
    for (int k = 0; k < 3; ++k) { float tv = V[k][0]; V[k][0] = V[k][2]; V[k][2] = tv; } }
  if (l1 < l2) { float tl = l1; l1 = l2; l2 = tl;
#pragma unroll
    for (int k = 0; k < 3; ++k) { float tv = V[k][1]; V[k][1] = V[k][2]; V[k][2] = tv; } }
  const float sig0 = sqrtf(fmaxf(l0, 0.0f));
  const float sig1 = sqrtf(fmaxf(l1, 0.0f));
  const float sig2 = sqrtf(fmaxf(l2, 0.0f));

  float v0[3] = {V[0][0], V[1][0], V[2][0]};
  float v1[3] = {V[0][1], V[1][1], V[2][1]};
  float v2[3] = {V[0][2], V[1][2], V[2][2]};
  float u0[3], u1[3], u2r[3];
#pragma unroll
  for (int i = 0; i < 3; ++i) {
    u0[i]  = A[i][0] * v0[0] + A[i][1] * v0[1] + A[i][2] * v0[2];
    u1[i]  = A[i][0] * v1[0] + A[i][1] * v1[1] + A[i][2] * v1[2];
    u2r[i] = A[i][0] * v2[0] + A[i][1] * v2[1] + A[i][2] * v2[2];
  }
  float n0 = u0[0] * u0[0] + u0[1] * u0[1] + u0[2] * u0[2];
  if (n0 > 1e-28f) { float inv = 1.0f / sqrtf(n0); u0[0] *= inv; u0[1] *= inv; u0[2] *= inv; }
  else { u0[0] = 1.0f; u0[1] = 0.0f; u0[2] = 0.0f; }
  float d01 = u1[0] * u0[0] + u1[1] * u0[1] + u1[2] * u0[2];
  u1[0] -= d01 * u0[0]; u1[1] -= d01 * u0[1]; u1[2] -= d01 * u0[2];
  float n1 = u1[0] * u1[0] + u1[1] * u1[1] + u1[2] * u1[2];
  if (n1 > 1e-28f) { float inv = 1.0f / sqrtf(n1); u1[0] *= inv; u1[1] *= inv; u1[2] *= inv; }
  else {
    float ex[3] = {1, 0, 0}, ey[3] = {0, 1, 0};
    const float* e = (fabsf(u0[0]) < 0.9f) ? ex : ey;
    u1[0] = u0[1] * e[2] - u0[2] * e[1];
    u1[1] = u0[2] * e[0] - u0[0] * e[2];
    u1[2] = u0[0] * e[1] - u0[1] * e[0];
    float nn = u1[0] * u1[0] + u1[1] * u1[1] + u1[2] * u1[2];
    float inv = 1.0f / sqrtf(nn);
    u1[0] *= inv; u1[1] *= inv; u1[2] *= inv;
  }
  float u2[3] = {u0[1] * u1[2] - u0[2] * u1[1],
                 u0[2] * u1[0] - u0[0] * u1[2],
                 u0[0] * u1[1] - u0[1] * u1[0]};
  float d2 = u2[0] * u2r[0] + u2[1] * u2r[1] + u2[2] * u2r[2];
  if (d2 < 0.0f) { u2[0] = -u2[0]; u2[1] = -u2[1]; u2[2] = -u2[2]; }

  const float scale = (sig0 + sig1 + sig2) / fmaxf(var_sum, 1e-30f);
  float R[3][3];
#pragma unroll
  for (int i = 0; i < 3; ++i)
#pragma unroll
    for (int j = 0; j < 3; ++j)
      R[i][j] = u0[i] * v0[j] + u1[i] * v1[j] + u2[i] * v2[j];
  const float Tx = dmx - scale * (R[0][0] * smx + R[0][1] * smy + R[0][2] * smz);
  const float Ty = dmy - scale * (R[1][0] * smx + R[1][1] * smy + R[1][2] * smz);
  const float Tz = dmz - scale * (R[2][0] * smx + R[2][1] * smy + R[2][2] * smz);
#pragma unroll
  for (int i = 0; i < 3; ++i)
#pragma unroll
    for (int j = 0; j < 3; ++j) bc[3 * i + j] = R[i][j];
  bc[9] = scale; bc[10] = Tx; bc[11] = Ty; bc[12] = Tz;
}

// ---------- Fully fused: one WAVE per batch, single pass over HBM. ----------
// All 64 lanes hold the reduced moments after the butterfly (shfl_xor leaves
// the total in every lane), so the 3x3 solve runs redundantly-but-uniformly
// on all lanes: no serial lane, no LDS, no barrier, no broadcast.
__global__ __launch_bounds__(256) void geo_fused_wave(const float* __restrict__ kp,
                                                      const int* __restrict__ perm,
                                                      float* __restrict__ partials, int B) {
  const int wave = (blockIdx.x << 2) | (threadIdx.x >> 6);
  if (wave >= B) return;
  const int lane = threadIdx.x & 63;
  const float4* s4 = (const float4*)kp + (size_t)wave * 192 + lane * 3;
  const float4* d4 = (const float4*)kp + (size_t)perm[wave] * 192 + lane * 3;
  const float4 a0 = s4[0], a1 = s4[1], a2 = s4[2];
  const float4 b0 = d4[0], b1 = d4[1], b2 = d4[2];
  const float s[12] = {a0.x, a0.y, a0.z, a0.w, a1.x, a1.y, a1.z, a1.w, a2.x, a2.y, a2.z, a2.w};
  const float d[12] = {b0.x, b0.y, b0.z, b0.w, b1.x, b1.y, b1.z, b1.w, b2.x, b2.y, b2.z, b2.w};

  // 16 moments: Ssrc(3) Sdst(3) M_ij (9) q (1)
  float r[16];
#pragma unroll
  for (int k = 0; k < 16; ++k) r[k] = 0.0f;
#pragma unroll
  for (int p = 0; p < 4; ++p) {
    const float sx = s[3 * p + 0], sy = s[3 * p + 1], sz = s[3 * p + 2];
    const float dx = d[3 * p + 0], dy = d[3 * p + 1], dz = d[3 * p + 2];
    r[0] += sx; r[1] += sy; r[2] += sz;
    r[3] += dx; r[4] += dy; r[5] += dz;
    r[6] += dx * sx; r[7] += dx * sy; r[8] += dx * sz;
    r[9] += dy * sx; r[10] += dy * sy; r[11] += dy * sz;
    r[12] += dz * sx; r[13] += dz * sy; r[14] += dz * sz;
    r[15] += sx * sx + sy * sy + sz * sz;
  }
#pragma unroll
  for (int k = 0; k < 16; ++k) r[k] = wredf(r[k]);

  // Wave-uniform solve (every lane has identical moments -> identical result).
  float bc[13];
  solve_rst(r, bc);

  const float sc = bc[9];
  float acc = 0.0f;
#pragma unroll
  for (int p = 0; p < 4; ++p) {
    const float sx = s[3 * p + 0], sy = s[3 * p + 1], sz = s[3 * p + 2];
    const float dx = d[3 * p + 0], dy = d[3 * p + 1], dz = d[3 * p + 2];
    const float e0 = sc * (bc[0] * sx + bc[1] * sy + bc[2] * sz) + bc[10] - dx;
    const float e1 = sc * (bc[3] * sx + bc[4] * sy + bc[5] * sz) + bc[11] - dy;
    const float e2 = sc * (bc[6] * sx + bc[7] * sy + bc[8] * sz) + bc[12] - dz;
    acc += fabsf(e0) + fabsf(e1) + fabsf(e2);
  }
  acc = wredf(acc);
  if (lane == 0) partials[wave] = acc;
}

// ---------- Final reduce ----------
__global__ __launch_bounds__(1024) void geo_fin(const float* __restrict__ partials,
                                                float* __restrict__ out, int n,
                                                double inv_total) {
  const int t = threadIdx.x;
  double acc = 0.0;
  for (int i = t; i < n; i += 1024) acc += (double)partials[i];
#pragma unroll
  for (int off = 32; off; off >>= 1) acc += __shfl_xor(acc, off, 64);
  __shared__ double sred[16];
  if ((t & 63) == 0) sred[t >> 6] = acc;
  __syncthreads();
  if (t == 0) {
    double tot = 0.0;
#pragma unroll
    for (int k = 0; k < 16; ++k) tot += sred[k];
    out[0] = (float)(tot * inv_total);
  }
}

extern "C" void kernel_launch(void* const* d_in, const int* in_sizes, int n_in,
                              void* d_out, int out_size, void* d_ws, size_t ws_size,
                              hipStream_t stream) {
  const float* kp = (const float*)d_in[0];
  const int* perm = (const int*)d_in[1];
  float* out = (float*)d_out;
  const int B = in_sizes[1];
  const double inv_total = 1.0 / ((double)B * (double)GEO_N * 3.0);

  float* partials = (float*)d_ws;  // B floats (ws_size is far larger)
  const int gridW = (B + 3) / 4;   // one wave per batch, 4 waves/block
  geo_fused_wave<<<gridW, 256, 0, stream>>>(kp, perm, partials, B);
  geo_fin<<<1, 1024, 0, stream>>>(partials, out, B, inv_total);
}

// Round 4
// 68.047 us; speedup vs baseline: 1.7149x; 1.7149x over previous
//
#include <hip/hip_runtime.h>
#include <math.h>

#define GEO_N 256
#define P_BATCH 16  // batches per wave (solve amortization factor)

__device__ __forceinline__ float wredf(float v) {
#pragma unroll
  for (int off = 32; off; off >>= 1) v += __shfl_xor(v, off, 64);
  return v;
}

// One Jacobi rotation on symmetric G (both sides) + accumulate into V.
template <int P, int Q>
__device__ __forceinline__ void jrot(float G[3][3], float V[3][3]) {
  float apq = G[P][Q];
  if (fabsf(apq) < 1e-22f) return;
  float tau = (G[Q][Q] - G[P][P]) / (2.0f * apq);
  float tt = sqrtf(1.0f + tau * tau);
  float t = (tau >= 0.0f) ? (1.0f / (tau + tt)) : (1.0f / (tau - tt));
  float c = 1.0f / sqrtf(1.0f + t * t);
  float s = t * c;
#pragma unroll
  for (int k = 0; k < 3; ++k) {
    float gkp = G[k][P], gkq = G[k][Q];
    G[k][P] = c * gkp - s * gkq;
    G[k][Q] = s * gkp + c * gkq;
  }
#pragma unroll
  for (int k = 0; k < 3; ++k) {
    float gpk = G[P][k], gqk = G[Q][k];
    G[P][k] = c * gpk - s * gqk;
    G[Q][k] = s * gpk + c * gqk;
  }
#pragma unroll
  for (int k = 0; k < 3; ++k) {
    float vkp = V[k][P], vkq = V[k][Q];
    V[k][P] = c * vkp - s * vkq;
    V[k][Q] = s * vkp + c * vkq;
  }
}

// From 16 raw moment sums -> R(9), scale, T(3) packed into bc[0..12].
// s0: Ssrc(3) Sdst(3) M_ij=sum dst_i*src_j (9, row-major i) q=sum|src|^2 (1)
// All indices compile-time -> registers, no scratch. Zero moments -> benign
// (Jacobi breaks immediately, fallback branches produce finite values).
__device__ __forceinline__ void solve_rst(const float s0[16], float bc[13]) {
  const float invN = 1.0f / (float)GEO_N;
  const float smx = s0[0] * invN, smy = s0[1] * invN, smz = s0[2] * invN;
  const float dmx = s0[3] * invN, dmy = s0[4] * invN, dmz = s0[5] * invN;
  float A[3][3];
  A[0][0] = s0[6] * invN - dmx * smx;  A[0][1] = s0[7] * invN - dmx * smy;  A[0][2] = s0[8] * invN - dmx * smz;
  A[1][0] = s0[9] * invN - dmy * smx;  A[1][1] = s0[10] * invN - dmy * smy; A[1][2] = s0[11] * invN - dmy * smz;
  A[2][0] = s0[12] * invN - dmz * smx; A[2][1] = s0[13] * invN - dmz * smy; A[2][2] = s0[14] * invN - dmz * smz;
  const float var_sum = s0[15] * invN - (smx * smx + smy * smy + smz * smz);

  float G[3][3];
#pragma unroll
  for (int i = 0; i < 3; ++i)
#pragma unroll
    for (int j = 0; j < 3; ++j)
      G[i][j] = A[0][i] * A[0][j] + A[1][i] * A[1][j] + A[2][i] * A[2][j];
  float V[3][3] = {{1, 0, 0}, {0, 1, 0}, {0, 0, 1}};
#pragma unroll 1
  for (int sweep = 0; sweep < 8; ++sweep) {
    float off = G[0][1] * G[0][1] + G[0][2] * G[0][2] + G[1][2] * G[1][2];
    float dia = G[0][0] * G[0][0] + G[1][1] * G[1][1] + G[2][2] * G[2][2];
    if (off <= 1e-13f * dia + 1e-30f) break;
    jrot<0, 1>(G, V);
    jrot<0, 2>(G, V);
    jrot<1, 2>(G, V);
  }
  float l0 = G[0][0], l1 = G[1][1], l2 = G[2][2];
  if (l0 < l1) { float tl = l0; l0 = l1; l1 = tl;
#pragma unroll
    for (int k = 0; k < 3; ++k) { float tv = V[k][0]; V[k][0] = V[k][1]; V[k][1] = tv; } }
  if (l0 < l2) { float tl = l0; l0 = l2; l2 = tl;
#pragma unroll
    for (int k = 0; k < 3; ++k) { float tv = V[k][0]; V[k][0] = V[k][2]; V[k][2] = tv; } }
  if (l1 < l2) { float tl = l1; l1 = l2; l2 = tl;
#pragma unroll
    for (int k = 0; k < 3; ++k) { float tv = V[k][1]; V[k][1] = V[k][2]; V[k][2] = tv; } }
  const float sig0 = sqrtf(fmaxf(l0, 0.0f));
  const float sig1 = sqrtf(fmaxf(l1, 0.0f));
  const float sig2 = sqrtf(fmaxf(l2, 0.0f));

  float v0[3] = {V[0][0], V[1][0], V[2][0]};
  float v1[3] = {V[0][1], V[1][1], V[2][1]};
  float v2[3] = {V[0][2], V[1][2], V[2][2]};
  float u0[3], u1[3], u2r[3];
#pragma unroll
  for (int i = 0; i < 3; ++i) {
    u0[i]  = A[i][0] * v0[0] + A[i][1] * v0[1] + A[i][2] * v0[2];
    u1[i]  = A[i][0] * v1[0] + A[i][1] * v1[1] + A[i][2] * v1[2];
    u2r[i] = A[i][0] * v2[0] + A[i][1] * v2[1] + A[i][2] * v2[2];
  }
  float n0 = u0[0] * u0[0] + u0[1] * u0[1] + u0[2] * u0[2];
  if (n0 > 1e-28f) { float inv = 1.0f / sqrtf(n0); u0[0] *= inv; u0[1] *= inv; u0[2] *= inv; }
  else { u0[0] = 1.0f; u0[1] = 0.0f; u0[2] = 0.0f; }
  float d01 = u1[0] * u0[0] + u1[1] * u0[1] + u1[2] * u0[2];
  u1[0] -= d01 * u0[0]; u1[1] -= d01 * u0[1]; u1[2] -= d01 * u0[2];
  float n1 = u1[0] * u1[0] + u1[1] * u1[1] + u1[2] * u1[2];
  if (n1 > 1e-28f) { float inv = 1.0f / sqrtf(n1); u1[0] *= inv; u1[1] *= inv; u1[2] *= inv; }
  else {
    float ex[3] = {1, 0, 0}, ey[3] = {0, 1, 0};
    const float* e = (fabsf(u0[0]) < 0.9f) ? ex : ey;
    u1[0] = u0[1] * e[2] - u0[2] * e[1];
    u1[1] = u0[2] * e[0] - u0[0] * e[2];
    u1[2] = u0[0] * e[1] - u0[1] * e[0];
    float nn = u1[0] * u1[0] + u1[1] * u1[1] + u1[2] * u1[2];
    float inv = 1.0f / sqrtf(nn);
    u1[0] *= inv; u1[1] *= inv; u1[2] *= inv;
  }
  float u2[3] = {u0[1] * u1[2] - u0[2] * u1[1],
                 u0[2] * u1[0] - u0[0] * u1[2],
                 u0[0] * u1[1] - u0[1] * u1[0]};
  float d2 = u2[0] * u2r[0] + u2[1] * u2r[1] + u2[2] * u2r[2];
  if (d2 < 0.0f) { u2[0] = -u2[0]; u2[1] = -u2[1]; u2[2] = -u2[2]; }

  const float scale = (sig0 + sig1 + sig2) / fmaxf(var_sum, 1e-30f);
  float R[3][3];
#pragma unroll
  for (int i = 0; i < 3; ++i)
#pragma unroll
    for (int j = 0; j < 3; ++j)
      R[i][j] = u0[i] * v0[j] + u1[i] * v1[j] + u2[i] * v2[j];
  const float Tx = dmx - scale * (R[0][0] * smx + R[0][1] * smy + R[0][2] * smz);
  const float Ty = dmy - scale * (R[1][0] * smx + R[1][1] * smy + R[1][2] * smz);
  const float Tz = dmz - scale * (R[2][0] * smx + R[2][1] * smy + R[2][2] * smz);
#pragma unroll
  for (int i = 0; i < 3; ++i)
#pragma unroll
    for (int j = 0; j < 3; ++j) bc[3 * i + j] = R[i][j];
  bc[9] = scale; bc[10] = Tx; bc[11] = Ty; bc[12] = Tz;
}

// ---------- Fused, solve amortized 16x via lane-parking. ----------
// Each wave owns P_BATCH consecutive batches. Phase 1: per batch, butterfly-
// reduce 16 moments (total lands in ALL lanes) and park batch i's moments in
// lane i's registers. Phase 2: every lane runs ONE solve on its parked
// moments (lanes >= count hold zeros -> benign). Phase 3: re-walk batches,
// broadcasting params from lane i via shfl; points re-read (L3-resident).
__global__ __launch_bounds__(256) void geo_fused16(const float* __restrict__ kp,
                                                   const int* __restrict__ perm,
                                                   float* __restrict__ partials,
                                                   int B, int NW) {
  const int wid = (blockIdx.x << 2) | (threadIdx.x >> 6);
  if (wid >= NW) return;
  const int lane = threadIdx.x & 63;
  const int b0 = wid * P_BATCH;
  const int count = min(P_BATCH, B - b0);
  const float4* base = (const float4*)kp;

  float m[16];
#pragma unroll
  for (int k = 0; k < 16; ++k) m[k] = 0.0f;

  // ---- Phase 1: moments, with explicit next-batch prefetch ----
  {
    const float4* s4 = base + (size_t)b0 * 192 + lane * 3;
    const float4* d4 = base + (size_t)perm[b0] * 192 + lane * 3;
    float4 A0 = s4[0], A1 = s4[1], A2 = s4[2];
    float4 C0 = d4[0], C1 = d4[1], C2 = d4[2];
#pragma unroll 1
    for (int i = 0; i < count; ++i) {
      float4 N0, N1, N2, M0, M1, M2;
      const int bn = b0 + i + 1;
      if (i + 1 < count) {
        const float4* sn = base + (size_t)bn * 192 + lane * 3;
        const float4* dn = base + (size_t)perm[bn] * 192 + lane * 3;
        N0 = sn[0]; N1 = sn[1]; N2 = sn[2];
        M0 = dn[0]; M1 = dn[1]; M2 = dn[2];
      }
      const float s[12] = {A0.x, A0.y, A0.z, A0.w, A1.x, A1.y, A1.z, A1.w, A2.x, A2.y, A2.z, A2.w};
      const float d[12] = {C0.x, C0.y, C0.z, C0.w, C1.x, C1.y, C1.z, C1.w, C2.x, C2.y, C2.z, C2.w};
      float r[16];
#pragma unroll
      for (int k = 0; k < 16; ++k) r[k] = 0.0f;
#pragma unroll
      for (int p = 0; p < 4; ++p) {
        const float sx = s[3 * p + 0], sy = s[3 * p + 1], sz = s[3 * p + 2];
        const float dx = d[3 * p + 0], dy = d[3 * p + 1], dz = d[3 * p + 2];
        r[0] += sx; r[1] += sy; r[2] += sz;
        r[3] += dx; r[4] += dy; r[5] += dz;
        r[6] += dx * sx; r[7] += dx * sy; r[8] += dx * sz;
        r[9] += dy * sx; r[10] += dy * sy; r[11] += dy * sz;
        r[12] += dz * sx; r[13] += dz * sy; r[14] += dz * sz;
        r[15] += sx * sx + sy * sy + sz * sz;
      }
#pragma unroll
      for (int k = 0; k < 16; ++k) r[k] = wredf(r[k]);
      if (lane == i) {
#pragma unroll
        for (int k = 0; k < 16; ++k) m[k] = r[k];
      }
      A0 = N0; A1 = N1; A2 = N2; C0 = M0; C1 = M1; C2 = M2;
    }
  }

  // ---- Phase 2: one solve per lane (16 useful solves per wave) ----
  float p[13];
  solve_rst(m, p);

  // ---- Phase 3: errors, params broadcast from lane i ----
  float acc = 0.0f;
  {
    const float4* s4 = base + (size_t)b0 * 192 + lane * 3;
    const float4* d4 = base + (size_t)perm[b0] * 192 + lane * 3;
    float4 A0 = s4[0], A1 = s4[1], A2 = s4[2];
    float4 C0 = d4[0], C1 = d4[1], C2 = d4[2];
#pragma unroll 1
    for (int i = 0; i < count; ++i) {
      float4 N0, N1, N2, M0, M1, M2;
      const int bn = b0 + i + 1;
      if (i + 1 < count) {
        const float4* sn = base + (size_t)bn * 192 + lane * 3;
        const float4* dn = base + (size_t)perm[bn] * 192 + lane * 3;
        N0 = sn[0]; N1 = sn[1]; N2 = sn[2];
        M0 = dn[0]; M1 = dn[1]; M2 = dn[2];
      }
      const float R00 = __shfl(p[0], i, 64), R01 = __shfl(p[1], i, 64), R02 = __shfl(p[2], i, 64);
      const float R10 = __shfl(p[3], i, 64), R11 = __shfl(p[4], i, 64), R12 = __shfl(p[5], i, 64);
      const float R20 = __shfl(p[6], i, 64), R21 = __shfl(p[7], i, 64), R22 = __shfl(p[8], i, 64);
      const float sc  = __shfl(p[9], i, 64);
      const float Tx  = __shfl(p[10], i, 64), Ty = __shfl(p[11], i, 64), Tz = __shfl(p[12], i, 64);
      const float s[12] = {A0.x, A0.y, A0.z, A0.w, A1.x, A1.y, A1.z, A1.w, A2.x, A2.y, A2.z, A2.w};
      const float d[12] = {C0.x, C0.y, C0.z, C0.w, C1.x, C1.y, C1.z, C1.w, C2.x, C2.y, C2.z, C2.w};
#pragma unroll
      for (int q = 0; q < 4; ++q) {
        const float sx = s[3 * q + 0], sy = s[3 * q + 1], sz = s[3 * q + 2];
        const float dx = d[3 * q + 0], dy = d[3 * q + 1], dz = d[3 * q + 2];
        const float e0 = sc * (R00 * sx + R01 * sy + R02 * sz) + Tx - dx;
        const float e1 = sc * (R10 * sx + R11 * sy + R12 * sz) + Ty - dy;
        const float e2 = sc * (R20 * sx + R21 * sy + R22 * sz) + Tz - dz;
        acc += fabsf(e0) + fabsf(e1) + fabsf(e2);
      }
      A0 = N0; A1 = N1; A2 = N2; C0 = M0; C1 = M1; C2 = M2;
    }
  }
  acc = wredf(acc);
  if (lane == 0) partials[wid] = acc;
}

// ---------- Final reduce ----------
__global__ __launch_bounds__(1024) void geo_fin(const float* __restrict__ partials,
                                                float* __restrict__ out, int n,
                                                double inv_total) {
  const int t = threadIdx.x;
  double acc = 0.0;
  for (int i = t; i < n; i += 1024) acc += (double)partials[i];
#pragma unroll
  for (int off = 32; off; off >>= 1) acc += __shfl_xor(acc, off, 64);
  __shared__ double sred[16];
  if ((t & 63) == 0) sred[t >> 6] = acc;
  __syncthreads();
  if (t == 0) {
    double tot = 0.0;
#pragma unroll
    for (int k = 0; k < 16; ++k) tot += sred[k];
    out[0] = (float)(tot * inv_total);
  }
}

extern "C" void kernel_launch(void* const* d_in, const int* in_sizes, int n_in,
                              void* d_out, int out_size, void* d_ws, size_t ws_size,
                              hipStream_t stream) {
  const float* kp = (const float*)d_in[0];
  const int* perm = (const int*)d_in[1];
  float* out = (float*)d_out;
  const int B = in_sizes[1];
  const double inv_total = 1.0 / ((double)B * (double)GEO_N * 3.0);

  const int NW = (B + P_BATCH - 1) / P_BATCH;  // waves (= partials)
  float* partials = (float*)d_ws;
  const int grid = (NW + 3) / 4;  // 4 waves per 256-thread block
  geo_fused16<<<grid, 256, 0, stream>>>(kp, perm, partials, B, NW);
  geo_fin<<<1, 1024, 0, stream>>>(partials, out, NW, inv_total);
}